// Round 3
// baseline (229.507 us; speedup 1.0000x reference)
//
#include <hip/hip_runtime.h>
#include <math.h>

#define INV2PI 0.15915494309189535f  // 1/(2*pi)

// ---------------------------------------------------------------------------
// Kernel 1 (v3): sums.  lanes = d (each lane owns 4 consecutive d's per chunk).
// Block = 512 threads = 8 waves = 4 neurons x 2 b-halves.  Grid = 512.
// Per chunk (256 d's): stage x[64][256] in LDS (conflict-free b128 writes and
// reads); iw' = INV2PI/(1+|W|), bp' = B_p*INV2PI live in 8 VGPRs per lane
// (coalesced global float4 loads) -- NO LDS reads for W/Bp at all.
// Hot loop (per b, fully unrolled over 32 b's): 1 ds_read_b128 + 4x
// {fma, fract, v_cos, v_sin, 2 adds}.  acc[32] static-indexed in VGPRs.
// Epilogue: per-wave private LDS slice (reuses x_s), XOR-swizzled transpose
// reduce + shfl_xor(32), then rotation by t:
//   sum cos(2pi*a + t) = cos(t)*A_c - sin(t)*A_s   (exact identity)
// Output: S2[n*64 + b] = (cos_sum, sin_sum).
// ---------------------------------------------------------------------------
__global__ __launch_bounds__(512, 4) void k_sums(
    const float* __restrict__ x, const float* __restrict__ t,
    const float* __restrict__ W, const float* __restrict__ Bp,
    float2* __restrict__ S2)
{
    __shared__ float x_s[64 * 256];   // 64 KB: [b][dd] for current d-chunk

    const int tid  = threadIdx.x;
    const int lane = tid & 63;
    const int wid  = __builtin_amdgcn_readfirstlane(tid >> 6);  // 0..7
    const int nl   = wid & 3;          // neuron within block
    const int bh   = wid >> 2;         // b-half (0: b 0..31, 1: b 32..63)
    const int n    = blockIdx.x * 4 + nl;

    float accC[32], accS[32];
    #pragma unroll
    for (int j = 0; j < 32; ++j) { accC[j] = 0.f; accS[j] = 0.f; }

    const float4* x4 = reinterpret_cast<const float4*>(x);

    for (int c = 0; c < 4; ++c) {
        __syncthreads();   // previous chunk fully consumed before overwrite

        // ---- stage x chunk: 16384 float4, linear LDS, coalesced global ----
        #pragma unroll
        for (int i = 0; i < 32; ++i) {
            int f4 = i * 512 + tid;        // 0..16383
            int b  = f4 >> 6;              // 64 float4 per row-chunk
            int dq = f4 & 63;
            float4 v = x4[b * 256 + c * 64 + dq];
            *reinterpret_cast<float4*>(&x_s[f4 << 2]) = v;
        }

        // ---- this chunk's iw'/bp' for neuron n: 8 VGPRs, global coalesced --
        float4 w4 = *reinterpret_cast<const float4*>(W  + (size_t)n * 1024 + c * 256 + 4 * lane);
        float4 b4 = *reinterpret_cast<const float4*>(Bp + (size_t)n * 1024 + c * 256 + 4 * lane);
        float4 iw, bp;
        iw.x = INV2PI / (1.f + fabsf(w4.x));
        iw.y = INV2PI / (1.f + fabsf(w4.y));
        iw.z = INV2PI / (1.f + fabsf(w4.z));
        iw.w = INV2PI / (1.f + fabsf(w4.w));
        bp.x = b4.x * INV2PI;
        bp.y = b4.y * INV2PI;
        bp.z = b4.z * INV2PI;
        bp.w = b4.w * INV2PI;

        __syncthreads();   // x chunk staged

        // ---- hot loop: 32 b's (this wave's half), fully unrolled ----------
        #pragma unroll
        for (int j = 0; j < 32; ++j) {
            const float4 xv = *reinterpret_cast<const float4*>(
                &x_s[(bh * 32 + j) * 256 + 4 * lane]);
            float a, r;
            a = fmaf(xv.x, iw.x, bp.x); r = __builtin_amdgcn_fractf(a);
            accC[j] += __builtin_amdgcn_cosf(r);
            accS[j] += __builtin_amdgcn_sinf(r);
            a = fmaf(xv.y, iw.y, bp.y); r = __builtin_amdgcn_fractf(a);
            accC[j] += __builtin_amdgcn_cosf(r);
            accS[j] += __builtin_amdgcn_sinf(r);
            a = fmaf(xv.z, iw.z, bp.z); r = __builtin_amdgcn_fractf(a);
            accC[j] += __builtin_amdgcn_cosf(r);
            accS[j] += __builtin_amdgcn_sinf(r);
            a = fmaf(xv.w, iw.w, bp.w); r = __builtin_amdgcn_fractf(a);
            accC[j] += __builtin_amdgcn_cosf(r);
            accS[j] += __builtin_amdgcn_sinf(r);
        }
    }

    // ---- epilogue: cross-lane reduce of acc[32] over 64 lanes -------------
    __syncthreads();                       // all waves done with x_s
    float* sl = x_s + (wid << 11);         // private 2048-float slice per wave
    const int bm = lane & 31;
    const int kb = (lane >> 5) << 5;       // lanes 0-31 sum k 0..31; 32-63: 32..63

    // phase C  (XOR col swizzle -> conflict-free writes and reads)
    #pragma unroll
    for (int j = 0; j < 32; ++j) sl[j * 64 + (lane ^ j)] = accC[j];
    float sumC = 0.f;
    #pragma unroll
    for (int k = 0; k < 32; ++k) sumC += sl[bm * 64 + ((kb + k) ^ bm)];
    // phase S  (same private slice; in-wave ordering is safe)
    #pragma unroll
    for (int j = 0; j < 32; ++j) sl[j * 64 + (lane ^ j)] = accS[j];
    float sumS = 0.f;
    #pragma unroll
    for (int k = 0; k < 32; ++k) sumS += sl[bm * 64 + ((kb + k) ^ bm)];

    sumC += __shfl_xor(sumC, 32);
    sumS += __shfl_xor(sumS, 32);

    if (lane < 32) {
        const int b  = bh * 32 + lane;
        const float tv = t[b];
        const float ct = cosf(tv), st = sinf(tv);
        S2[n * 64 + b] = make_float2(ct * sumC - st * sumS,
                                     st * sumC + ct * sumS);
    }
}

// ---------------------------------------------------------------------------
// Kernel 2: split-K GEMM.  out^T[d][b] = sum_n Pr[d][n]*c[n][b] + Pi[d][n]*s[n][b]
// grid = (64 d-tiles of 16, 8 k-chunks of 256).  Each wave: 4 d-rows, lanes=b.
// Pr/Pi rows are wave-uniform -> scalar loads; S2 loads coalesced float2.
// Writes f32 partials [s][d][b] (coalesced).
// ---------------------------------------------------------------------------
__global__ __launch_bounds__(256, 4) void k_gemm(
    const float2* __restrict__ S2, const float* __restrict__ Pr,
    const float* __restrict__ Pi, float* __restrict__ partial)
{
    const int lane = threadIdx.x & 63;
    const int wid  = __builtin_amdgcn_readfirstlane(threadIdx.x >> 6);
    const int d0   = blockIdx.x * 16 + wid * 4;
    const int k0   = blockIdx.y * 256;

    const float* pr = Pr + (size_t)d0 * 2048 + k0;
    const float* pi = Pi + (size_t)d0 * 2048 + k0;

    float a0 = 0.f, a1 = 0.f, a2 = 0.f, a3 = 0.f;

    for (int kk = 0; kk < 256; kk += 4) {
        float2 cs[4];
        #pragma unroll
        for (int i = 0; i < 4; ++i)
            cs[i] = S2[(size_t)(k0 + kk + i) * 64 + lane];
        #pragma unroll
        for (int i = 0; i < 4; ++i) {
            a0 += pr[kk + i]        * cs[i].x + pi[kk + i]        * cs[i].y;
            a1 += pr[2048 + kk + i] * cs[i].x + pi[2048 + kk + i] * cs[i].y;
            a2 += pr[4096 + kk + i] * cs[i].x + pi[4096 + kk + i] * cs[i].y;
            a3 += pr[6144 + kk + i] * cs[i].x + pi[6144 + kk + i] * cs[i].y;
        }
    }

    float* p = partial + ((size_t)blockIdx.y * 1024 + d0) * 64 + lane;
    p[0]   = a0;
    p[64]  = a1;
    p[128] = a2;
    p[192] = a3;
}

// ---------------------------------------------------------------------------
// Kernel 3 (v2): reduce 8 split-K partials + SiLU, write out[b][d].
// grid = 256 blocks x 256 thr; wave -> (b, 64-d tile); lane -> d.
// Gather reads from L2-resident partial (stride-64 float, L2 absorbs),
// 8 independent loads for ILP, coalesced final store.
// ---------------------------------------------------------------------------
__global__ __launch_bounds__(256, 4) void k_reduce_silu(
    const float* __restrict__ partial, float* __restrict__ out)
{
    const int lane = threadIdx.x & 63;
    const int gw   = blockIdx.x * 4 + (threadIdx.x >> 6);  // 0..1023
    const int b    = gw >> 4;
    const int d    = ((gw & 15) << 6) + lane;

    float s = 0.f;
    #pragma unroll
    for (int ss = 0; ss < 8; ++ss)
        s += partial[((size_t)ss * 1024 + d) * 64 + b];

    float sig = 1.0f / (1.0f + __expf(-s));
    out[(size_t)b * 1024 + d] = s * sig;
}

// ---------------------------------------------------------------------------
extern "C" void kernel_launch(void* const* d_in, const int* in_sizes, int n_in,
                              void* d_out, int out_size, void* d_ws, size_t ws_size,
                              hipStream_t stream)
{
    const float* x  = (const float*)d_in[0];   // (64,1024)
    const float* t  = (const float*)d_in[1];   // (64,)
    const float* W  = (const float*)d_in[2];   // (2048,1024)
    const float* Bp = (const float*)d_in[3];   // (2048,1024)
    const float* Pr = (const float*)d_in[4];   // (1024,2048)
    const float* Pi = (const float*)d_in[5];   // (1024,2048)
    // d_in[6], d_in[7]: sin/cos LUT — superseded by hardware v_sin/v_cos

    float*  out     = (float*)d_out;                       // (64,1024) f32
    float2* S2      = (float2*)d_ws;                       // 2048*64 float2 = 1 MB
    float*  partial = (float*)((char*)d_ws + (1 << 20));   // 8*1024*64 f32 = 2 MB

    k_sums<<<512, 512, 0, stream>>>(x, t, W, Bp, S2);
    k_gemm<<<dim3(64, 8), 256, 0, stream>>>(S2, Pr, Pi, partial);
    k_reduce_silu<<<256, 256, 0, stream>>>(partial, out);
}

// Round 4
// 164.728 us; speedup vs baseline: 1.3932x; 1.3932x over previous
//
#include <hip/hip_runtime.h>
#include <math.h>

#define INV2PI 0.15915494309189535f  // 1/(2*pi)

// ---------------------------------------------------------------------------
// Kernel 1 (v4): sums.  lanes = d (each lane owns 4 consecutive d's per chunk).
// Block = 512 threads = 8 waves = 2 neurons x 4 b-quarters (16 b per wave).
// Grid = 1024 (2 neurons per block).
// Per chunk (256 d's): stage x[64][256] in LDS (4096 float4s, i<8 -- the
// round-3 i<32 overran both x and the LDS allocation 4x!);
// iw' = INV2PI/(1+|W|), bp' = B_p*INV2PI live in 8 VGPRs/lane (coalesced
// float4 global loads) -- zero LDS traffic for W/Bp.
// Hot loop per b: 1 ds_read_b128 + 4x {fma, fract, v_cos, v_sin, 2 adds}.
// acc[16][2] = 32 VGPRs (halved vs round 3 to kill spills; no launch_bounds
// min-waves clamp -- round 3's (512,4) forced VGPR=64 and spilled acc to
// scratch: 52 MB WRITE_SIZE).
// Epilogue: per-wave XOR-swizzled LDS transpose (reuses x_s) + shfl_xor(16,32),
// then rotation by t (exact identity):
//   sum cos(2pi*a + t) = cos(t)*A_c - sin(t)*A_s
// Output: S2[n*64 + b] = (cos_sum, sin_sum).
// ---------------------------------------------------------------------------
__global__ __launch_bounds__(512) void k_sums(
    const float* __restrict__ x, const float* __restrict__ t,
    const float* __restrict__ W, const float* __restrict__ Bp,
    float2* __restrict__ S2)
{
    __shared__ float x_s[64 * 256];   // 64 KB: [b][dd] for current d-chunk

    const int tid  = threadIdx.x;
    const int lane = tid & 63;
    const int wid  = __builtin_amdgcn_readfirstlane(tid >> 6);  // 0..7
    const int nl   = wid & 1;          // neuron within block
    const int bq   = wid >> 1;         // b-quarter (16 b's)
    const int n    = blockIdx.x * 2 + nl;

    float accC[16], accS[16];
    #pragma unroll
    for (int j = 0; j < 16; ++j) { accC[j] = 0.f; accS[j] = 0.f; }

    const float4* x4 = reinterpret_cast<const float4*>(x);

    for (int c = 0; c < 4; ++c) {
        __syncthreads();   // previous chunk fully consumed before overwrite

        // ---- stage x chunk: 4096 float4, linear LDS, coalesced global ----
        #pragma unroll
        for (int i = 0; i < 8; ++i) {
            int f4 = i * 512 + tid;        // 0..4095
            int b  = f4 >> 6;              // 64 float4 per row-chunk
            int dq = f4 & 63;
            float4 v = x4[b * 256 + c * 64 + dq];
            *reinterpret_cast<float4*>(&x_s[f4 << 2]) = v;
        }

        // ---- this chunk's iw'/bp' for neuron n: 8 VGPRs, global coalesced --
        float4 w4 = *reinterpret_cast<const float4*>(W  + (size_t)n * 1024 + c * 256 + 4 * lane);
        float4 b4 = *reinterpret_cast<const float4*>(Bp + (size_t)n * 1024 + c * 256 + 4 * lane);
        float4 iw, bp;
        iw.x = INV2PI / (1.f + fabsf(w4.x));
        iw.y = INV2PI / (1.f + fabsf(w4.y));
        iw.z = INV2PI / (1.f + fabsf(w4.z));
        iw.w = INV2PI / (1.f + fabsf(w4.w));
        bp.x = b4.x * INV2PI;
        bp.y = b4.y * INV2PI;
        bp.z = b4.z * INV2PI;
        bp.w = b4.w * INV2PI;

        __syncthreads();   // x chunk staged

        // ---- hot loop: this wave's 16 b's, fully unrolled ----------------
        #pragma unroll
        for (int j = 0; j < 16; ++j) {
            const float4 xv = *reinterpret_cast<const float4*>(
                &x_s[(bq * 16 + j) * 256 + 4 * lane]);
            float a, r;
            a = fmaf(xv.x, iw.x, bp.x); r = __builtin_amdgcn_fractf(a);
            accC[j] += __builtin_amdgcn_cosf(r);
            accS[j] += __builtin_amdgcn_sinf(r);
            a = fmaf(xv.y, iw.y, bp.y); r = __builtin_amdgcn_fractf(a);
            accC[j] += __builtin_amdgcn_cosf(r);
            accS[j] += __builtin_amdgcn_sinf(r);
            a = fmaf(xv.z, iw.z, bp.z); r = __builtin_amdgcn_fractf(a);
            accC[j] += __builtin_amdgcn_cosf(r);
            accS[j] += __builtin_amdgcn_sinf(r);
            a = fmaf(xv.w, iw.w, bp.w); r = __builtin_amdgcn_fractf(a);
            accC[j] += __builtin_amdgcn_cosf(r);
            accS[j] += __builtin_amdgcn_sinf(r);
        }
    }

    // ---- epilogue: reduce acc[16] across 64 lanes ------------------------
    __syncthreads();                       // all waves done reading x_s
    float* sl = x_s + (wid << 11);         // private 2048-float slice per wave

    // write: row j (b within quarter), col = lane ^ j  (bijective, spread)
    #pragma unroll
    for (int j = 0; j < 16; ++j) {
        int col = (lane ^ j) & 63;
        *reinterpret_cast<float2*>(&sl[j * 128 + 2 * col]) =
            make_float2(accC[j], accS[j]);
    }
    // read: lane (g = lane>>4, bb = lane&15) sums source lanes g*16..g*16+15
    const int g  = lane >> 4;
    const int bb = lane & 15;
    float sC = 0.f, sS = 0.f;
    #pragma unroll
    for (int k = 0; k < 16; ++k) {
        int src = g * 16 + k;
        int col = (src ^ bb) & 63;
        float2 v = *reinterpret_cast<const float2*>(&sl[bb * 128 + 2 * col]);
        sC += v.x; sS += v.y;
    }
    sC += __shfl_xor(sC, 16);
    sS += __shfl_xor(sS, 16);
    sC += __shfl_xor(sC, 32);
    sS += __shfl_xor(sS, 32);

    if (lane < 16) {
        const int b  = bq * 16 + lane;
        const float tv = t[b];
        const float ct = cosf(tv), st = sinf(tv);
        S2[n * 64 + b] = make_float2(ct * sC - st * sS,
                                     st * sC + ct * sS);
    }
}

// ---------------------------------------------------------------------------
// Kernel 2: split-K GEMM.  out^T[d][b] = sum_n Pr[d][n]*c[n][b] + Pi[d][n]*s[n][b]
// grid = (64 d-tiles of 16, 8 k-chunks of 256).  Each wave: 4 d-rows, lanes=b.
// Pr/Pi rows are wave-uniform -> scalar loads; S2 loads coalesced float2.
// Writes f32 partials [s][d][b] (coalesced).
// ---------------------------------------------------------------------------
__global__ __launch_bounds__(256, 4) void k_gemm(
    const float2* __restrict__ S2, const float* __restrict__ Pr,
    const float* __restrict__ Pi, float* __restrict__ partial)
{
    const int lane = threadIdx.x & 63;
    const int wid  = __builtin_amdgcn_readfirstlane(threadIdx.x >> 6);
    const int d0   = blockIdx.x * 16 + wid * 4;
    const int k0   = blockIdx.y * 256;

    const float* pr = Pr + (size_t)d0 * 2048 + k0;
    const float* pi = Pi + (size_t)d0 * 2048 + k0;

    float a0 = 0.f, a1 = 0.f, a2 = 0.f, a3 = 0.f;

    for (int kk = 0; kk < 256; kk += 4) {
        float2 cs[4];
        #pragma unroll
        for (int i = 0; i < 4; ++i)
            cs[i] = S2[(size_t)(k0 + kk + i) * 64 + lane];
        #pragma unroll
        for (int i = 0; i < 4; ++i) {
            a0 += pr[kk + i]        * cs[i].x + pi[kk + i]        * cs[i].y;
            a1 += pr[2048 + kk + i] * cs[i].x + pi[2048 + kk + i] * cs[i].y;
            a2 += pr[4096 + kk + i] * cs[i].x + pi[4096 + kk + i] * cs[i].y;
            a3 += pr[6144 + kk + i] * cs[i].x + pi[6144 + kk + i] * cs[i].y;
        }
    }

    float* p = partial + ((size_t)blockIdx.y * 1024 + d0) * 64 + lane;
    p[0]   = a0;
    p[64]  = a1;
    p[128] = a2;
    p[192] = a3;
}

// ---------------------------------------------------------------------------
// Kernel 3: reduce 8 split-K partials + SiLU, write out[b][d].
// grid = 256 blocks x 256 thr; wave -> (b, 64-d tile); lane -> d.
// ---------------------------------------------------------------------------
__global__ __launch_bounds__(256, 4) void k_reduce_silu(
    const float* __restrict__ partial, float* __restrict__ out)
{
    const int lane = threadIdx.x & 63;
    const int gw   = blockIdx.x * 4 + (threadIdx.x >> 6);  // 0..1023
    const int b    = gw >> 4;
    const int d    = ((gw & 15) << 6) + lane;

    float s = 0.f;
    #pragma unroll
    for (int ss = 0; ss < 8; ++ss)
        s += partial[((size_t)ss * 1024 + d) * 64 + b];

    float sig = 1.0f / (1.0f + __expf(-s));
    out[(size_t)b * 1024 + d] = s * sig;
}

// ---------------------------------------------------------------------------
extern "C" void kernel_launch(void* const* d_in, const int* in_sizes, int n_in,
                              void* d_out, int out_size, void* d_ws, size_t ws_size,
                              hipStream_t stream)
{
    const float* x  = (const float*)d_in[0];   // (64,1024)
    const float* t  = (const float*)d_in[1];   // (64,)
    const float* W  = (const float*)d_in[2];   // (2048,1024)
    const float* Bp = (const float*)d_in[3];   // (2048,1024)
    const float* Pr = (const float*)d_in[4];   // (1024,2048)
    const float* Pi = (const float*)d_in[5];   // (1024,2048)
    // d_in[6], d_in[7]: sin/cos LUT — superseded by hardware v_sin/v_cos

    float*  out     = (float*)d_out;                       // (64,1024) f32
    float2* S2      = (float2*)d_ws;                       // 2048*64 float2 = 1 MB
    float*  partial = (float*)((char*)d_ws + (1 << 20));   // 8*1024*64 f32 = 2 MB

    k_sums<<<1024, 512, 0, stream>>>(x, t, W, Bp, S2);
    k_gemm<<<dim3(64, 8), 256, 0, stream>>>(S2, Pr, Pi, partial);
    k_reduce_silu<<<256, 256, 0, stream>>>(partial, out);
}

// Round 5
// 164.509 us; speedup vs baseline: 1.3951x; 1.0013x over previous
//
#include <hip/hip_runtime.h>
#include <math.h>

#define INV2PI 0.15915494309189535f  // 1/(2*pi)

// ---------------------------------------------------------------------------
// Kernel 1 (v5): sums.  lanes = d (each lane owns 2 consecutive d's per chunk).
// Block = 512 threads = 8 waves = 2 neurons x 4 b-quarters (16 b per wave).
// Grid = 1024.  Chunk = 128 d's -> x_s = 32 KB -> 4 blocks/CU = 32 waves/CU
// (round-4's 64 KB chunk capped occupancy at 2 blocks/CU = 38%; trans-pipe
// stalls were exposed).  Hot loop per b: 1 ds_read_b64 + 2x {fma, fract,
// v_cos, v_sin, 2 adds}.  acc[16][2] = 32 VGPRs, iw/bp in 4 VGPRs (coalesced
// float2 global loads, zero LDS traffic for W/Bp).
// Trans model (measured r4): v_sin/v_cos ~16 cyc/wave64 -> issue floor ~34 us;
// occupancy 8 waves/SIMD should get busy% to ~85+.
// Epilogue: two passes (C then S) through a per-wave 1024-float LDS slice
// (XOR col swizzle, 2-way max = free), shfl_xor(16,32), then rotation by t:
//   sum cos(2pi*a + t) = cos(t)*A_c - sin(t)*A_s   (exact identity)
// Output: S2[n*64 + b] = (cos_sum, sin_sum).
// ---------------------------------------------------------------------------
__global__ __launch_bounds__(512) void k_sums(
    const float* __restrict__ x, const float* __restrict__ t,
    const float* __restrict__ W, const float* __restrict__ Bp,
    float2* __restrict__ S2)
{
    __shared__ float x_s[64 * 128];   // 32 KB: [b][dd] for current d-chunk

    const int tid  = threadIdx.x;
    const int lane = tid & 63;
    const int wid  = __builtin_amdgcn_readfirstlane(tid >> 6);  // 0..7
    const int nl   = wid & 1;          // neuron within block
    const int bq   = wid >> 1;         // b-quarter (16 b's)
    const int n    = blockIdx.x * 2 + nl;

    float accC[16], accS[16];
    #pragma unroll
    for (int j = 0; j < 16; ++j) { accC[j] = 0.f; accS[j] = 0.f; }

    const float4* x4 = reinterpret_cast<const float4*>(x);

    for (int c = 0; c < 8; ++c) {
        __syncthreads();   // previous chunk fully consumed before overwrite

        // ---- stage x chunk: 64 b x 32 float4 = 2048 float4s ----
        #pragma unroll
        for (int i = 0; i < 4; ++i) {
            int f4 = i * 512 + tid;        // 0..2047
            int b  = f4 >> 5;              // 32 float4 per row-chunk
            int dq = f4 & 31;
            float4 v = x4[b * 256 + c * 32 + dq];
            *reinterpret_cast<float4*>(&x_s[f4 << 2]) = v;
        }

        // ---- this chunk's iw'/bp': 4 VGPRs, global coalesced ----
        float2 w2 = *reinterpret_cast<const float2*>(W  + (size_t)n * 1024 + c * 128 + 2 * lane);
        float2 b2 = *reinterpret_cast<const float2*>(Bp + (size_t)n * 1024 + c * 128 + 2 * lane);
        const float iwx = INV2PI / (1.f + fabsf(w2.x));
        const float iwy = INV2PI / (1.f + fabsf(w2.y));
        const float bpx = b2.x * INV2PI;
        const float bpy = b2.y * INV2PI;

        __syncthreads();   // x chunk staged

        // ---- hot loop: this wave's 16 b's, fully unrolled ----
        #pragma unroll
        for (int j = 0; j < 16; ++j) {
            const float2 xv = *reinterpret_cast<const float2*>(
                &x_s[(bq * 16 + j) * 128 + 2 * lane]);
            float a, r;
            a = fmaf(xv.x, iwx, bpx); r = __builtin_amdgcn_fractf(a);
            accC[j] += __builtin_amdgcn_cosf(r);
            accS[j] += __builtin_amdgcn_sinf(r);
            a = fmaf(xv.y, iwy, bpy); r = __builtin_amdgcn_fractf(a);
            accC[j] += __builtin_amdgcn_cosf(r);
            accS[j] += __builtin_amdgcn_sinf(r);
        }
    }

    // ---- epilogue: reduce acc[16] across 64 lanes (two passes) ------------
    __syncthreads();                       // all waves done reading x_s
    float* sl = x_s + (wid << 10);         // private 1024-float slice per wave
    const int g  = lane >> 4;
    const int bb = lane & 15;

    // pass C: write row j at col lane^j (bijective, <=2-way bank alias = free)
    #pragma unroll
    for (int j = 0; j < 16; ++j) sl[j * 64 + (lane ^ j)] = accC[j];
    float sC = 0.f;
    #pragma unroll
    for (int k = 0; k < 16; ++k) sC += sl[bb * 64 + ((g * 16 + k) ^ bb)];

    // pass S (same slice; in-wave write-after-read ordering is preserved)
    #pragma unroll
    for (int j = 0; j < 16; ++j) sl[j * 64 + (lane ^ j)] = accS[j];
    float sS = 0.f;
    #pragma unroll
    for (int k = 0; k < 16; ++k) sS += sl[bb * 64 + ((g * 16 + k) ^ bb)];

    sC += __shfl_xor(sC, 16);
    sS += __shfl_xor(sS, 16);
    sC += __shfl_xor(sC, 32);
    sS += __shfl_xor(sS, 32);

    if (lane < 16) {
        const int b  = bq * 16 + lane;
        const float tv = t[b];
        const float ct = cosf(tv), st = sinf(tv);
        S2[n * 64 + b] = make_float2(ct * sC - st * sS,
                                     st * sC + ct * sS);
    }
}

// ---------------------------------------------------------------------------
// Kernel 2 (v2): split-K GEMM.
// out^T[d][b] = sum_n Pr[d][n]*c[n][b] + Pi[d][n]*s[n][b]
// grid = (128 d-tiles of 8, 8 k-chunks of 256) = 1024 blocks -> 4 waves/SIMD
// (r4 had 512 blocks = 2/SIMD, latency-exposed).  Each wave: 2 d-rows,
// lanes = b.  Pr/Pi wave-uniform -> s_load; S2 coalesced float2, 8 in flight.
// Writes f32 partials [s][d][b] (coalesced).
// ---------------------------------------------------------------------------
__global__ __launch_bounds__(256) void k_gemm(
    const float2* __restrict__ S2, const float* __restrict__ Pr,
    const float* __restrict__ Pi, float* __restrict__ partial)
{
    const int lane = threadIdx.x & 63;
    const int wid  = __builtin_amdgcn_readfirstlane(threadIdx.x >> 6);
    const int d0   = blockIdx.x * 8 + wid * 2;
    const int k0   = blockIdx.y * 256;

    const float* pr = Pr + (size_t)d0 * 2048 + k0;
    const float* pi = Pi + (size_t)d0 * 2048 + k0;

    float a0 = 0.f, a1 = 0.f;

    for (int kk = 0; kk < 256; kk += 8) {
        float2 cs[8];
        #pragma unroll
        for (int i = 0; i < 8; ++i)
            cs[i] = S2[(size_t)(k0 + kk + i) * 64 + lane];
        #pragma unroll
        for (int i = 0; i < 8; ++i) {
            a0 += pr[kk + i]        * cs[i].x + pi[kk + i]        * cs[i].y;
            a1 += pr[2048 + kk + i] * cs[i].x + pi[2048 + kk + i] * cs[i].y;
        }
    }

    float* p = partial + ((size_t)blockIdx.y * 1024 + d0) * 64 + lane;
    p[0]  = a0;
    p[64] = a1;
}

// ---------------------------------------------------------------------------
// Kernel 3: reduce 8 split-K partials + SiLU, write out[b][d].
// grid = 256 blocks x 256 thr; wave -> (b, 64-d tile); lane -> d.
// ---------------------------------------------------------------------------
__global__ __launch_bounds__(256, 4) void k_reduce_silu(
    const float* __restrict__ partial, float* __restrict__ out)
{
    const int lane = threadIdx.x & 63;
    const int gw   = blockIdx.x * 4 + (threadIdx.x >> 6);  // 0..1023
    const int b    = gw >> 4;
    const int d    = ((gw & 15) << 6) + lane;

    float s = 0.f;
    #pragma unroll
    for (int ss = 0; ss < 8; ++ss)
        s += partial[((size_t)ss * 1024 + d) * 64 + b];

    float sig = 1.0f / (1.0f + __expf(-s));
    out[(size_t)b * 1024 + d] = s * sig;
}

// ---------------------------------------------------------------------------
extern "C" void kernel_launch(void* const* d_in, const int* in_sizes, int n_in,
                              void* d_out, int out_size, void* d_ws, size_t ws_size,
                              hipStream_t stream)
{
    const float* x  = (const float*)d_in[0];   // (64,1024)
    const float* t  = (const float*)d_in[1];   // (64,)
    const float* W  = (const float*)d_in[2];   // (2048,1024)
    const float* Bp = (const float*)d_in[3];   // (2048,1024)
    const float* Pr = (const float*)d_in[4];   // (1024,2048)
    const float* Pi = (const float*)d_in[5];   // (1024,2048)
    // d_in[6], d_in[7]: sin/cos LUT — superseded by hardware v_sin/v_cos

    float*  out     = (float*)d_out;                       // (64,1024) f32
    float2* S2      = (float2*)d_ws;                       // 2048*64 float2 = 1 MB
    float*  partial = (float*)((char*)d_ws + (1 << 20));   // 8*1024*64 f32 = 2 MB

    k_sums<<<1024, 512, 0, stream>>>(x, t, W, Bp, S2);
    k_gemm<<<dim3(128, 8), 256, 0, stream>>>(S2, Pr, Pi, partial);
    k_reduce_silu<<<256, 256, 0, stream>>>(partial, out);
}